// Round 4
// baseline (205.754 us; speedup 1.0000x reference)
//
#include <hip/hip_runtime.h>
#include <math.h>

namespace {

constexpr int D  = 128;
constexpr int H  = 8;
constexpr int TN = 64;

// d_ws layout (requires ws_size >= 34.6 MB):
//   N  [128][1024] f32  (0.25 * WQ_h @ WK_h^T, stacked over h)   512 KB
//   M  [1024][128] f32  (WV_h @ WO_h, stacked over h)            512 KB
//   QS [B][1024]   f32  (qk, overwritten in-place by s in K2)     32 MB

// ---------------- K0: precompute N and M (tiny) ----------------
__global__ __launch_bounds__(256)
void k0_nm(const float* __restrict__ WQ, const float* __restrict__ WK,
           const float* __restrict__ WV, const float* __restrict__ WO,
           float* __restrict__ Nmat, float* __restrict__ Mmat)
{
    const int t = blockIdx.x * 256 + threadIdx.x;   // 0..131071
    {   // N[k][h*128+d] = 0.25 * sum_j WQ[k][h*16+j] * WK[d][h*16+j]
        const int k = t >> 10, col = t & 1023;
        const int h = col >> 7, d = col & 127;
        const float* wq = WQ + (size_t)k * D + h * 16;
        const float* wk = WK + (size_t)d * D + h * 16;
        float a = 0.f;
        #pragma unroll
        for (int j = 0; j < 16; ++j) a = fmaf(wq[j], wk[j], a);
        Nmat[t] = 0.25f * a;
    }
    {   // M[h*128+d][e] = sum_j WV[d][h*16+j] * WO[h*16+j][e]
        const int row = t >> 7, e = t & 127;
        const int h = row >> 7, d = row & 127;
        const float* wv = WV + (size_t)d * D + h * 16;
        const float* wo = WO + (size_t)(h * 16) * D + e;
        float a = 0.f;
        #pragma unroll
        for (int j = 0; j < 16; ++j) a = fmaf(wv[j], wo[(size_t)j * D], a);
        Mmat[t] = a;
    }
}

// ---------------- K1: qk = center @ N  ([8192,128]@[128,1024]) ----------------
__global__ __launch_bounds__(256)
void k1_qk(const float* __restrict__ center, const float* __restrict__ Nmat,
           float* __restrict__ qk)
{
    __shared__ float c_lds[8 * 128];      // 8 center rows
    const int tid = threadIdx.x;
    const size_t rb = (size_t)blockIdx.x * 8;

    ((float4*)c_lds)[tid] = ((const float4*)(center + rb * D))[tid];
    __syncthreads();

    const float4* Np = (const float4*)Nmat + tid;   // N[k][tid*4..]; row = 256 float4
    float4 acc[8];
    #pragma unroll
    for (int r = 0; r < 8; ++r) acc[r] = make_float4(0.f, 0.f, 0.f, 0.f);

    float4 bufA[4], bufB[4];
    #pragma unroll
    for (int i = 0; i < 4; ++i) bufA[i] = Np[(size_t)i * 256];

    #pragma unroll
    for (int g = 0; g < 32; ++g) {        // compile-time g -> static buffer select
        float4* cur = (g & 1) ? bufB : bufA;
        float4* nxt = (g & 1) ? bufA : bufB;
        if (g < 31) {
            #pragma unroll
            for (int i = 0; i < 4; ++i) nxt[i] = Np[(size_t)(g * 4 + 4 + i) * 256];
        }
        #pragma unroll
        for (int i = 0; i < 4; ++i) {
            const int k = g * 4 + i;
            const float4 nv = cur[i];
            #pragma unroll
            for (int r = 0; r < 8; ++r) {
                const float cc = c_lds[r * 128 + k];   // uniform broadcast
                acc[r].x = fmaf(cc, nv.x, acc[r].x);
                acc[r].y = fmaf(cc, nv.y, acc[r].y);
                acc[r].z = fmaf(cc, nv.z, acc[r].z);
                acc[r].w = fmaf(cc, nv.w, acc[r].w);
            }
        }
    }
    #pragma unroll
    for (int r = 0; r < 8; ++r)
        ((float4*)(qk + (rb + r) * 1024))[tid] = acc[r];
}

// ---------------- K2: stream neighbors; softmax; s = attn-weighted token sum ----------------
__global__ __launch_bounds__(256)
void k2_stream(const float* __restrict__ center, const float* __restrict__ neighbors,
               float* __restrict__ qs /* in: qk, out: s (in-place per batch) */)
{
    __shared__ float qk_lds[4][H * 128];   // 16 KB
    __shared__ float c_lds[4][D];          //  2 KB
    __shared__ float P_lds[4][TN][8];      //  8 KB

    const int w  = threadIdx.x >> 6;
    const int l  = threadIdx.x & 63;
    const int b  = blockIdx.x * 4 + w;
    const int hi = l >> 5;
    const int dd = l & 31;
    const int c4 = dd << 2;

    float* qsb = qs + (size_t)b * 1024;
    float* qkw = qk_lds[w];

    // early prefetch of my token's first 8 float4 (HBM critical path)
    const float4* nbrow = reinterpret_cast<const float4*>(neighbors + ((size_t)b * TN + l) * D);
    float4 nrowA[8], nrowB[8];
    #pragma unroll
    for (int i = 0; i < 8; ++i) nrowA[i] = nbrow[i];

    // cooperative load qk[b] (4 KB) into LDS
    {
        const float4* qp = (const float4*)qsb;
        float4 t0 = qp[l], t1 = qp[64 + l], t2 = qp[128 + l], t3 = qp[192 + l];
        ((float4*)qkw)[l]       = t0;
        ((float4*)qkw)[64 + l]  = t1;
        ((float4*)qkw)[128 + l] = t2;
        ((float4*)qkw)[192 + l] = t3;
    }
    if (l < 32)
        *reinterpret_cast<float4*>(&c_lds[w][l << 2]) =
            *reinterpret_cast<const float4*>(center + (size_t)b * D + (l << 2));
    __syncthreads();

    // center-token score s0[h] (butterfly -> uniform)
    float s0[8];
    {
        const int d0 = l << 1;
        const float cx = c_lds[w][d0], cy = c_lds[w][d0 + 1];
        #pragma unroll
        for (int h = 0; h < 8; ++h) {
            const float2 qq = *reinterpret_cast<const float2*>(&qkw[h * 128 + d0]);
            float v = qq.x * cx + qq.y * cy;
            #pragma unroll
            for (int off = 32; off >= 1; off >>= 1) v += __shfl_xor(v, off);
            s0[h] = v;
        }
    }

    // pass 1: neighbor scores (token = lane), 2x8-deep pipeline
    float sc[8];
    #pragma unroll
    for (int h = 0; h < 8; ++h) sc[h] = 0.f;

    #define CONSUME_GROUP(ARR, BASE)                                                   \
        _Pragma("unroll")                                                              \
        for (int i = 0; i < 8; ++i) {                                                  \
            const float4 tv = ARR[i];                                                  \
            _Pragma("unroll")                                                          \
            for (int h = 0; h < 8; ++h) {                                              \
                const float4 k4 = *reinterpret_cast<const float4*>(&qkw[h * 128 + (BASE + i) * 4]); \
                sc[h] = fmaf(tv.x, k4.x, fmaf(tv.y, k4.y, fmaf(tv.z, k4.z, fmaf(tv.w, k4.w, sc[h])))); \
            }                                                                          \
        }

    #pragma unroll
    for (int i = 0; i < 8; ++i) nrowB[i] = nbrow[8 + i];
    CONSUME_GROUP(nrowA, 0)
    #pragma unroll
    for (int i = 0; i < 8; ++i) nrowA[i] = nbrow[16 + i];
    CONSUME_GROUP(nrowB, 8)
    #pragma unroll
    for (int i = 0; i < 8; ++i) nrowB[i] = nbrow[24 + i];
    CONSUME_GROUP(nrowA, 16)
    CONSUME_GROUP(nrowB, 24)
    #undef CONSUME_GROUP

    // softmax over 65 tokens
    float pctr[8], pmy[8];
    #pragma unroll
    for (int h = 0; h < 8; ++h) {
        float mv = sc[h];
        #pragma unroll
        for (int off = 32; off >= 1; off >>= 1) mv = fmaxf(mv, __shfl_xor(mv, off));
        mv = fmaxf(mv, s0[h]);
        const float pv = expf(sc[h] - mv);
        const float p0 = expf(s0[h] - mv);
        float sum = pv;
        #pragma unroll
        for (int off = 32; off >= 1; off >>= 1) sum += __shfl_xor(sum, off);
        const float inv = 1.0f / (sum + p0);
        pmy[h]  = pv * inv;
        pctr[h] = p0 * inv;
    }
    *reinterpret_cast<float4*>(&P_lds[w][l][0]) = make_float4(pmy[0], pmy[1], pmy[2], pmy[3]);
    *reinterpret_cast<float4*>(&P_lds[w][l][4]) = make_float4(pmy[4], pmy[5], pmy[6], pmy[7]);
    __syncthreads();

    // pass 2: s[h][c4..] = pctr[h]*center + sum_t p[t][h]*tok[t][c4..], halves split t
    {
        float4 sac[8];
        const float4 cv4 = *reinterpret_cast<const float4*>(&c_lds[w][c4]);
        const float seed = (hi == 0) ? 1.0f : 0.0f;   // center seeded once (round-2 lesson)
        #pragma unroll
        for (int h = 0; h < 8; ++h) {
            const float pc = pctr[h] * seed;
            sac[h].x = pc * cv4.x; sac[h].y = pc * cv4.y;
            sac[h].z = pc * cv4.z; sac[h].w = pc * cv4.w;
        }
        const float* nb2 = neighbors + (size_t)b * TN * D + (size_t)(hi * 32) * D + c4;
        float4 tbA[4], tbB[4];
        #pragma unroll
        for (int t = 0; t < 4; ++t) tbA[t] = *reinterpret_cast<const float4*>(nb2 + (size_t)t * D);
        #pragma unroll
        for (int g = 0; g < 8; ++g) {     // 8 groups of 4 tokens per half
            float4* curb = (g & 1) ? tbB : tbA;
            float4* nxtb = (g & 1) ? tbA : tbB;
            if (g < 7) {
                #pragma unroll
                for (int t = 0; t < 4; ++t)
                    nxtb[t] = *reinterpret_cast<const float4*>(nb2 + (size_t)(g * 4 + 4 + t) * D);
            }
            #pragma unroll
            for (int t = 0; t < 4; ++t) {
                const int tok = hi * 32 + g * 4 + t;
                const float4 tv = curb[t];
                const float4 pa = *reinterpret_cast<const float4*>(&P_lds[w][tok][0]);
                const float4 pb = *reinterpret_cast<const float4*>(&P_lds[w][tok][4]);
                const float p8[8] = {pa.x, pa.y, pa.z, pa.w, pb.x, pb.y, pb.z, pb.w};
                #pragma unroll
                for (int h = 0; h < 8; ++h) {
                    sac[h].x = fmaf(p8[h], tv.x, sac[h].x);
                    sac[h].y = fmaf(p8[h], tv.y, sac[h].y);
                    sac[h].z = fmaf(p8[h], tv.z, sac[h].z);
                    sac[h].w = fmaf(p8[h], tv.w, sac[h].w);
                }
            }
        }
        #pragma unroll
        for (int h = 0; h < 8; ++h) {
            sac[h].x += __shfl_xor(sac[h].x, 32);
            sac[h].y += __shfl_xor(sac[h].y, 32);
            sac[h].z += __shfl_xor(sac[h].z, 32);
            sac[h].w += __shfl_xor(sac[h].w, 32);
        }
        if (hi == 0) {
            #pragma unroll
            for (int h = 0; h < 8; ++h)
                *reinterpret_cast<float4*>(qsb + h * 128 + c4) = sac[h];
        }
    }
}

// ---------------- K3: out = s @ M  ([8192,1024]@[1024,128]) ----------------
__global__ __launch_bounds__(256)
void k3_out(const float* __restrict__ qs, const float* __restrict__ Mmat,
            float* __restrict__ out)
{
    __shared__ float s_lds[8 * 1024];   // 32 KB; reused as partial[8][8][128]
    const int tid = threadIdx.x;
    const size_t rb = (size_t)blockIdx.x * 8;

    {   // cooperative load of 8 s-rows
        const float4* sp = (const float4*)(qs + rb * 1024);
        #pragma unroll
        for (int i = 0; i < 8; ++i)
            ((float4*)s_lds)[i * 256 + tid] = sp[i * 256 + tid];
    }
    __syncthreads();

    const int cg = tid & 31;          // column group: cols cg*4..cg*4+3
    const int kg = tid >> 5;          // k-split group 0..7 (k-range kg*128..+127)
    const int c4 = cg << 2;
    const int kbase = kg << 7;
    const int rot = kg << 2;          // stagger: groups hit distinct LDS banks

    float4 acc[8];
    #pragma unroll
    for (int r = 0; r < 8; ++r) acc[r] = make_float4(0.f, 0.f, 0.f, 0.f);

    const float4* Mp4 = (const float4*)Mmat;    // M row = 32 float4

    float4 bA[4], bB[4];
    #pragma unroll
    for (int i = 0; i < 4; ++i) {
        const int k = kbase + ((0 * 4 + i + rot) & 127);
        bA[i] = Mp4[(size_t)k * 32 + cg];
    }
    #pragma unroll
    for (int g = 0; g < 32; ++g) {
        float4* cur = (g & 1) ? bB : bA;
        float4* nxt = (g & 1) ? bA : bB;
        if (g < 31) {
            #pragma unroll
            for (int i = 0; i < 4; ++i) {
                const int k = kbase + ((g * 4 + 4 + i + rot) & 127);
                nxt[i] = Mp4[(size_t)k * 32 + cg];
            }
        }
        #pragma unroll
        for (int i = 0; i < 4; ++i) {
            const int k = kbase + ((g * 4 + i + rot) & 127);
            const float4 mv = cur[i];
            #pragma unroll
            for (int r = 0; r < 8; ++r) {
                const float sv = s_lds[r * 1024 + k];
                acc[r].x = fmaf(sv, mv.x, acc[r].x);
                acc[r].y = fmaf(sv, mv.y, acc[r].y);
                acc[r].z = fmaf(sv, mv.z, acc[r].z);
                acc[r].w = fmaf(sv, mv.w, acc[r].w);
            }
        }
    }
    __syncthreads();                  // all s_lds reads done; reuse as partials
    float* part = s_lds;              // part[kg][r][128]
    #pragma unroll
    for (int r = 0; r < 8; ++r)
        *reinterpret_cast<float4*>(&part[(kg * 8 + r) * 128 + c4]) = acc[r];
    __syncthreads();

    {   // reduce 8 partials; thread -> (row r = tid>>5, cols c4)
        const int r = tid >> 5;
        float4 sum = make_float4(0.f, 0.f, 0.f, 0.f);
        #pragma unroll
        for (int g = 0; g < 8; ++g) {
            const float4 p = *reinterpret_cast<const float4*>(&part[(g * 8 + r) * 128 + c4]);
            sum.x += p.x; sum.y += p.y; sum.z += p.z; sum.w += p.w;
        }
        *reinterpret_cast<float4*>(out + (rb + r) * D + c4) = sum;
    }
}

} // namespace

extern "C" void kernel_launch(void* const* d_in, const int* in_sizes, int n_in,
                              void* d_out, int out_size, void* d_ws, size_t ws_size,
                              hipStream_t stream) {
    const float* center    = (const float*)d_in[0];
    const float* neighbors = (const float*)d_in[1];
    const float* WQ        = (const float*)d_in[2];
    const float* WK        = (const float*)d_in[3];
    const float* WV        = (const float*)d_in[4];
    const float* WO        = (const float*)d_in[5];
    float* outp            = (float*)d_out;

    const int B = in_sizes[0] / D;   // 8192

    float* Nmat = (float*)d_ws;                 // 128*1024
    float* Mmat = Nmat + 128 * 1024;            // 1024*128
    float* QS   = Mmat + 1024 * 128;            // B*1024 (qk, then s in-place)
    // requires ws_size >= (262144 + B*1024)*4 = ~34.6 MB

    hipLaunchKernelGGL(k0_nm,    dim3(512),     dim3(256), 0, stream, WQ, WK, WV, WO, Nmat, Mmat);
    hipLaunchKernelGGL(k1_qk,    dim3(B / 8),   dim3(256), 0, stream, center, Nmat, QS);
    hipLaunchKernelGGL(k2_stream,dim3(B / 4),   dim3(256), 0, stream, center, neighbors, QS);
    hipLaunchKernelGGL(k3_out,   dim3(B / 8),   dim3(256), 0, stream, QS, Mmat, outp);
}

// Round 5
// 161.643 us; speedup vs baseline: 1.2729x; 1.2729x over previous
//
#include <hip/hip_runtime.h>
#include <math.h>

namespace {

constexpr int D  = 128;
constexpr int H  = 8;
constexpr int TN = 64;

// d_ws layout (requires ws_size >= 34.6 MB):
//   N  [128][1024] f32  (0.25 * WQ_h @ WK_h^T, stacked over h)   512 KB
//   M  [1024][128] f32  (WV_h @ WO_h, stacked over h)            512 KB
//   QS [B][1024]   f32  (qk, overwritten in-place by s in K2)     32 MB

// ---------------- K0: precompute N and M (tiny) ----------------
__global__ __launch_bounds__(256)
void k0_nm(const float* __restrict__ WQ, const float* __restrict__ WK,
           const float* __restrict__ WV, const float* __restrict__ WO,
           float* __restrict__ Nmat, float* __restrict__ Mmat)
{
    const int t = blockIdx.x * 256 + threadIdx.x;   // 0..131071
    {   // N[k][h*128+d] = 0.25 * sum_j WQ[k][h*16+j] * WK[d][h*16+j]
        const int k = t >> 10, col = t & 1023;
        const int h = col >> 7, d = col & 127;
        const float* wq = WQ + (size_t)k * D + h * 16;
        const float* wk = WK + (size_t)d * D + h * 16;
        float a = 0.f;
        #pragma unroll
        for (int j = 0; j < 16; ++j) a = fmaf(wq[j], wk[j], a);
        Nmat[t] = 0.25f * a;
    }
    {   // M[h*128+d][e] = sum_j WV[d][h*16+j] * WO[h*16+j][e]
        const int row = t >> 7, e = t & 127;
        const int h = row >> 7, d = row & 127;
        const float* wv = WV + (size_t)d * D + h * 16;
        const float* wo = WO + (size_t)(h * 16) * D + e;
        float a = 0.f;
        #pragma unroll
        for (int j = 0; j < 16; ++j) a = fmaf(wv[j], wo[(size_t)j * D], a);
        Mmat[t] = a;
    }
}

// ---------------- K1: qk = center @ N  ([8192,128]@[128,1024]) ----------------
__global__ __launch_bounds__(256)
void k1_qk(const float* __restrict__ center, const float* __restrict__ Nmat,
           float* __restrict__ qk)
{
    __shared__ float c_lds[8 * 128];      // 8 center rows
    const int tid = threadIdx.x;
    const size_t rb = (size_t)blockIdx.x * 8;

    ((float4*)c_lds)[tid] = ((const float4*)(center + rb * D))[tid];
    __syncthreads();

    const float4* Np = (const float4*)Nmat + tid;   // N[k][tid*4..]; row = 256 float4
    float4 acc[8];
    #pragma unroll
    for (int r = 0; r < 8; ++r) acc[r] = make_float4(0.f, 0.f, 0.f, 0.f);

    float4 bufA[4], bufB[4];
    #pragma unroll
    for (int i = 0; i < 4; ++i) bufA[i] = Np[(size_t)i * 256];

    #pragma unroll
    for (int g = 0; g < 32; ++g) {        // compile-time g -> static buffer select
        float4* cur = (g & 1) ? bufB : bufA;
        float4* nxt = (g & 1) ? bufA : bufB;
        if (g < 31) {
            #pragma unroll
            for (int i = 0; i < 4; ++i) nxt[i] = Np[(size_t)(g * 4 + 4 + i) * 256];
        }
        #pragma unroll
        for (int i = 0; i < 4; ++i) {
            const int k = g * 4 + i;
            const float4 nv = cur[i];
            #pragma unroll
            for (int r = 0; r < 8; ++r) {
                const float cc = c_lds[r * 128 + k];   // uniform broadcast
                acc[r].x = fmaf(cc, nv.x, acc[r].x);
                acc[r].y = fmaf(cc, nv.y, acc[r].y);
                acc[r].z = fmaf(cc, nv.z, acc[r].z);
                acc[r].w = fmaf(cc, nv.w, acc[r].w);
            }
        }
    }
    #pragma unroll
    for (int r = 0; r < 8; ++r)
        ((float4*)(qk + (rb + r) * 1024))[tid] = acc[r];
}

// ---------------- K2 v2: one 128-thread block per batch; LDS-staged neighbors ----------------
// LDS: nb 32KB (XOR-swizzled f4 rows) + qk 4KB (reused for s-partial) + P 2KB + c 0.5KB
__global__ __launch_bounds__(128)
void k2_stream(const float* __restrict__ center, const float* __restrict__ neighbors,
               float* __restrict__ qs /* in: qk, out: s (in-place per batch) */)
{
    __shared__ float nb_lds[TN * D];       // 32 KB, f4-index: (t<<5) | (fc ^ (t&7))
    __shared__ float qk_lds[H * D];        // 4 KB; reused as s-partial buffer at the end
    __shared__ float P_lds[TN][8];         // 2 KB
    __shared__ float c_lds[D];             // 0.5 KB
    __shared__ float red[2][2][8];         // per-wave max/sum

    const int tid = threadIdx.x;           // 0..127
    const int w   = tid >> 6;              // wave 0/1
    const int l   = tid & 63;
    const int hi  = l >> 5;
    const int ll  = l & 31;
    const int b   = blockIdx.x;

    float*       qsb = qs + (size_t)b * 1024;
    const float4* gnb = (const float4*)(neighbors + (size_t)b * TN * D);

    // ---- stage: fully coalesced (each instr = 128 lanes x 16B = 2KB contiguous) ----
    float4 st[16];
    #pragma unroll
    for (int i = 0; i < 16; ++i) st[i] = gnb[i * 128 + tid];
    const float4 qv0 = ((const float4*)qsb)[tid];
    const float4 qv1 = ((const float4*)qsb)[128 + tid];
    float4 cv;
    if (tid < 32) cv = ((const float4*)(center + (size_t)b * D))[tid];

    #pragma unroll
    for (int i = 0; i < 16; ++i) {
        const int fi = i * 128 + tid;      // global f4 index 0..2047
        const int t  = fi >> 5;            // token row
        const int fc = fi & 31;            // f4 col
        ((float4*)nb_lds)[(t << 5) | (fc ^ (t & 7))] = st[i];
    }
    ((float4*)qk_lds)[tid]       = qv0;
    ((float4*)qk_lds)[128 + tid] = qv1;
    if (tid < 32) ((float4*)c_lds)[tid] = cv;
    __syncthreads();

    // ---- pass 1: wave w scores tokens w*32+ll; lane halves split d ----
    const int t1   = w * 32 + ll;
    const int t1rb = t1 << 5;
    const int t1sw = t1 & 7;
    float sc[8];
    #pragma unroll
    for (int h = 0; h < 8; ++h) sc[h] = 0.f;
    #pragma unroll
    for (int jj = 0; jj < 16; ++jj) {
        const int fc = hi * 16 + jj;
        const float4 tv = ((const float4*)nb_lds)[t1rb | (fc ^ t1sw)];
        #pragma unroll
        for (int h = 0; h < 8; ++h) {
            const float4 kv = ((const float4*)qk_lds)[h * 32 + fc];
            sc[h] = fmaf(tv.x, kv.x, fmaf(tv.y, kv.y, fmaf(tv.z, kv.z, fmaf(tv.w, kv.w, sc[h]))));
        }
    }
    #pragma unroll
    for (int h = 0; h < 8; ++h) sc[h] += __shfl_xor(sc[h], 32);   // combine d-halves

    // ---- center score s0[h] (both waves compute identically) ----
    float s0[8];
    {
        const float cx = c_lds[2 * l], cy = c_lds[2 * l + 1];
        #pragma unroll
        for (int h = 0; h < 8; ++h) {
            const float2 qq = *reinterpret_cast<const float2*>(&qk_lds[h * 128 + 2 * l]);
            float v = qq.x * cx + qq.y * cy;
            #pragma unroll
            for (int off = 32; off >= 1; off >>= 1) v += __shfl_xor(v, off);
            s0[h] = v;
        }
    }

    // ---- softmax over 65 tokens (2-wave combine via LDS) ----
    float mw[8];
    #pragma unroll
    for (int h = 0; h < 8; ++h) {
        float m = sc[h];
        #pragma unroll
        for (int off = 16; off >= 1; off >>= 1) m = fmaxf(m, __shfl_xor(m, off));
        mw[h] = m;                          // wave-local max over its 32 tokens
    }
    if (l == 0) {
        #pragma unroll
        for (int h = 0; h < 8; ++h) red[w][0][h] = mw[h];
    }
    __syncthreads();

    float pmy[8], pctr[8], e0[8], sw_[8];
    #pragma unroll
    for (int h = 0; h < 8; ++h) {
        const float m = fmaxf(fmaxf(red[0][0][h], red[1][0][h]), s0[h]);
        pmy[h] = __expf(sc[h] - m);         // unnormalized p for my token
        e0[h]  = __expf(s0[h] - m);
        float s = pmy[h];
        #pragma unroll
        for (int off = 16; off >= 1; off >>= 1) s += __shfl_xor(s, off);
        sw_[h] = s;                         // wave-local sum
    }
    if (l == 0) {
        #pragma unroll
        for (int h = 0; h < 8; ++h) red[w][1][h] = sw_[h];
    }
    __syncthreads();

    #pragma unroll
    for (int h = 0; h < 8; ++h) {
        const float inv = 1.0f / (red[0][1][h] + red[1][1][h] + e0[h]);
        pmy[h]  *= inv;
        pctr[h]  = e0[h] * inv;
    }
    if (hi == 0) {
        *reinterpret_cast<float4*>(&P_lds[t1][0]) = make_float4(pmy[0], pmy[1], pmy[2], pmy[3]);
        *reinterpret_cast<float4*>(&P_lds[t1][4]) = make_float4(pmy[4], pmy[5], pmy[6], pmy[7]);
    }
    __syncthreads();

    // ---- pass 2: wave w sums tokens [w*32, w*32+32); lane: col f4 = ll, hi splits 16+16 ----
    float4 acc[8];
    #pragma unroll
    for (int h = 0; h < 8; ++h) acc[h] = make_float4(0.f, 0.f, 0.f, 0.f);
    #pragma unroll
    for (int tt = 0; tt < 16; ++tt) {
        const int t2 = w * 32 + hi * 16 + tt;
        const float4 tv = ((const float4*)nb_lds)[(t2 << 5) | (ll ^ (t2 & 7))];
        const float4 pa = *reinterpret_cast<const float4*>(&P_lds[t2][0]);
        const float4 pb = *reinterpret_cast<const float4*>(&P_lds[t2][4]);
        const float p8[8] = {pa.x, pa.y, pa.z, pa.w, pb.x, pb.y, pb.z, pb.w};
        #pragma unroll
        for (int h = 0; h < 8; ++h) {
            acc[h].x = fmaf(p8[h], tv.x, acc[h].x);
            acc[h].y = fmaf(p8[h], tv.y, acc[h].y);
            acc[h].z = fmaf(p8[h], tv.z, acc[h].z);
            acc[h].w = fmaf(p8[h], tv.w, acc[h].w);
        }
    }
    #pragma unroll
    for (int h = 0; h < 8; ++h) {          // combine hi-halves
        acc[h].x += __shfl_xor(acc[h].x, 32);
        acc[h].y += __shfl_xor(acc[h].y, 32);
        acc[h].z += __shfl_xor(acc[h].z, 32);
        acc[h].w += __shfl_xor(acc[h].w, 32);
    }
    // cross-wave combine through qk_lds region (dead after softmax)
    if (w == 0 && hi == 0) {
        #pragma unroll
        for (int h = 0; h < 8; ++h) ((float4*)qk_lds)[h * 32 + ll] = acc[h];
    }
    __syncthreads();
    if (w == 1 && hi == 0) {
        const float4 cc = ((const float4*)c_lds)[ll];
        #pragma unroll
        for (int h = 0; h < 8; ++h) {
            const float4 p0 = ((const float4*)qk_lds)[h * 32 + ll];
            float4 o;
            o.x = p0.x + acc[h].x + pctr[h] * cc.x;
            o.y = p0.y + acc[h].y + pctr[h] * cc.y;
            o.z = p0.z + acc[h].z + pctr[h] * cc.z;
            o.w = p0.w + acc[h].w + pctr[h] * cc.w;
            *reinterpret_cast<float4*>(qsb + h * 128 + ll * 4) = o;
        }
    }
}

// ---------------- K3: out = s @ M  ([8192,1024]@[1024,128]) ----------------
__global__ __launch_bounds__(256)
void k3_out(const float* __restrict__ qs, const float* __restrict__ Mmat,
            float* __restrict__ out)
{
    __shared__ float s_lds[8 * 1024];   // 32 KB; reused as partial[8][8][128]
    const int tid = threadIdx.x;
    const size_t rb = (size_t)blockIdx.x * 8;

    {   // cooperative load of 8 s-rows
        const float4* sp = (const float4*)(qs + rb * 1024);
        #pragma unroll
        for (int i = 0; i < 8; ++i)
            ((float4*)s_lds)[i * 256 + tid] = sp[i * 256 + tid];
    }
    __syncthreads();

    const int cg = tid & 31;          // column group: cols cg*4..cg*4+3
    const int kg = tid >> 5;          // k-split group 0..7 (k-range kg*128..+127)
    const int c4 = cg << 2;
    const int kbase = kg << 7;
    const int rot = kg << 2;          // stagger: groups hit distinct LDS banks

    float4 acc[8];
    #pragma unroll
    for (int r = 0; r < 8; ++r) acc[r] = make_float4(0.f, 0.f, 0.f, 0.f);

    const float4* Mp4 = (const float4*)Mmat;    // M row = 32 float4

    float4 bA[4], bB[4];
    #pragma unroll
    for (int i = 0; i < 4; ++i) {
        const int k = kbase + ((0 * 4 + i + rot) & 127);
        bA[i] = Mp4[(size_t)k * 32 + cg];
    }
    #pragma unroll
    for (int g = 0; g < 32; ++g) {
        float4* cur = (g & 1) ? bB : bA;
        float4* nxt = (g & 1) ? bA : bB;
        if (g < 31) {
            #pragma unroll
            for (int i = 0; i < 4; ++i) {
                const int k = kbase + ((g * 4 + 4 + i + rot) & 127);
                nxt[i] = Mp4[(size_t)k * 32 + cg];
            }
        }
        #pragma unroll
        for (int i = 0; i < 4; ++i) {
            const int k = kbase + ((g * 4 + i + rot) & 127);
            const float4 mv = cur[i];
            #pragma unroll
            for (int r = 0; r < 8; ++r) {
                const float sv = s_lds[r * 1024 + k];
                acc[r].x = fmaf(sv, mv.x, acc[r].x);
                acc[r].y = fmaf(sv, mv.y, acc[r].y);
                acc[r].z = fmaf(sv, mv.z, acc[r].z);
                acc[r].w = fmaf(sv, mv.w, acc[r].w);
            }
        }
    }
    __syncthreads();                  // all s_lds reads done; reuse as partials
    float* part = s_lds;              // part[kg][r][128]
    #pragma unroll
    for (int r = 0; r < 8; ++r)
        *reinterpret_cast<float4*>(&part[(kg * 8 + r) * 128 + c4]) = acc[r];
    __syncthreads();

    {   // reduce 8 partials; thread -> (row r = tid>>5, cols c4)
        const int r = tid >> 5;
        float4 sum = make_float4(0.f, 0.f, 0.f, 0.f);
        #pragma unroll
        for (int g = 0; g < 8; ++g) {
            const float4 p = *reinterpret_cast<const float4*>(&part[(g * 8 + r) * 128 + c4]);
            sum.x += p.x; sum.y += p.y; sum.z += p.z; sum.w += p.w;
        }
        *reinterpret_cast<float4*>(out + (rb + r) * D + c4) = sum;
    }
}

} // namespace

extern "C" void kernel_launch(void* const* d_in, const int* in_sizes, int n_in,
                              void* d_out, int out_size, void* d_ws, size_t ws_size,
                              hipStream_t stream) {
    const float* center    = (const float*)d_in[0];
    const float* neighbors = (const float*)d_in[1];
    const float* WQ        = (const float*)d_in[2];
    const float* WK        = (const float*)d_in[3];
    const float* WV        = (const float*)d_in[4];
    const float* WO        = (const float*)d_in[5];
    float* outp            = (float*)d_out;

    const int B = in_sizes[0] / D;   // 8192

    float* Nmat = (float*)d_ws;                 // 128*1024
    float* Mmat = Nmat + 128 * 1024;            // 1024*128
    float* QS   = Mmat + 1024 * 128;            // B*1024 (qk, then s in-place)
    // requires ws_size >= (262144 + B*1024)*4 = ~34.6 MB

    hipLaunchKernelGGL(k0_nm,    dim3(512),   dim3(256), 0, stream, WQ, WK, WV, WO, Nmat, Mmat);
    hipLaunchKernelGGL(k1_qk,    dim3(B / 8), dim3(256), 0, stream, center, Nmat, QS);
    hipLaunchKernelGGL(k2_stream,dim3(B),     dim3(128), 0, stream, center, neighbors, QS);
    hipLaunchKernelGGL(k3_out,   dim3(B / 8), dim3(256), 0, stream, QS, Mmat, outp);
}